// Round 10
// baseline (91.853 us; speedup 1.0000x reference)
//
#include <hip/hip_runtime.h>
#include <hip/hip_bf16.h>
#include <hip/hip_fp16.h>
#include <math.h>

#define HH 4
#define BB 4
#define CC 32
#define VV 1000
#define LL 12
#define EE 20000
#define NBL (BB * LL)   /* 48 */
#define SS (HH * NBL)   /* 192 */
#define RCAP 128        /* padded CSR row capacity (max deg ~45 for this input) */
#define LALPHA 0.2f
#define NEG_CAP_F -9000000000000000.0f

typedef unsigned int uint;
typedef unsigned short ushort;

// ---------------------------------------------------------------------------
// k_h (fused with scatter): blocks x<500 compute h_g/s_src/s_dst; blocks
// x>=500 do the padded-CSR scatter (cnt pre-zeroed by hipMemsetAsync).
// h_g[slab][v][c] (f16), slab=h*NBL+b*LL+l. Block = 2v x 4h x 32c.
// ---------------------------------------------------------------------------
__global__ __launch_bounds__(256) void k_h(const float* __restrict__ x,
                                           const float* __restrict__ W,
                                           const float* __restrict__ a,
                                           ushort* __restrict__ h_g,
                                           float* __restrict__ s_src,
                                           float* __restrict__ s_dst,
                                           int* __restrict__ cnt,
                                           const int* __restrict__ ei,
                                           const float* __restrict__ ev,
                                           uint2* __restrict__ csr) {
  if (blockIdx.x >= 500) {
    int e = ((blockIdx.x - 500) * 4 + blockIdx.y) * 256 + threadIdx.x;
    if (e < EE) {
      int r = ei[e];
      int d = ei[EE + e];
      int pos = atomicAdd(&cnt[r], 1);
      if (pos < RCAP) {
        float lv = fmaxf(__logf(ev[e]), NEG_CAP_F);
        csr[r * RCAP + pos] = make_uint2((uint)d, __float_as_uint(lv));
      }
    }
    return;
  }

  __shared__ float W_lds[HH * CC * CC];   // 16 KB
  __shared__ float a_lds[HH * 2 * CC];    // 1 KB
  __shared__ float x_s[CC * 2 * LL];      // 3 KB (s-part only)
  __shared__ float wa[HH][2][CC];         // 512 B
  const int tid = threadIdx.x;
  const int b = blockIdx.y;
  const int v0 = blockIdx.x * 2;

  {
    const float4* Wf = (const float4*)W;
    float4* Wl = (float4*)W_lds;
    for (int i = tid; i < HH * CC * CC / 4; i += 256) Wl[i] = Wf[i];
  }
  a_lds[tid] = a[tid];   // HH*2*CC == 256
#pragma unroll
  for (int k = 0; k < 3; ++k) {
    int i = k * 256 + tid;
    int ci = i / 24, r = i - ci * 24;
    x_s[i] = x[(b * CC + ci) * (VV * LL) + v0 * LL + r];
  }
  __syncthreads();

  {
    int h = tid >> 6, which = (tid >> 5) & 1, ci = tid & 31;
    float acc = 0.f;
#pragma unroll
    for (int k = 0; k < CC; ++k) {
      int c = (k + ci) & 31;
      acc = fmaf(W_lds[h * CC * CC + ci * CC + c],
                 a_lds[h * 2 * CC + which * CC + c], acc);
    }
    wa[h][which][ci] = acc;
  }
  __syncthreads();

  const int vp = tid >> 7;          // wave-uniform
  const int h = (tid >> 5) & 3;
  const int c = tid & 31;
  const int v = v0 + vp;

  int xoff = (b * CC) * (VV * LL) + v * LL;
  xoff = __builtin_amdgcn_readfirstlane(xoff);
  const float* xr = x + xoff;

  float acc[LL];
#pragma unroll
  for (int l = 0; l < LL; ++l) acc[l] = 0.f;

#pragma unroll 4
  for (int ci = 0; ci < CC; ++ci) {
    float w = W_lds[h * CC * CC + ci * CC + c];
#pragma unroll
    for (int l = 0; l < LL; ++l)
      acc[l] = fmaf(xr[ci * (VV * LL) + l], w, acc[l]);
  }

  const int slab0 = h * NBL + b * LL;
#pragma unroll
  for (int l = 0; l < LL; ++l) {
    __half hv = __float2half(acc[l]);
    h_g[((size_t)(slab0 + l) * VV + v) * CC + c] = *(ushort*)&hv;
  }

  if (tid < 192) {
    int which = tid & 1;
    int t2 = tid >> 1;            // 0..95
    int l = t2 % 12;
    int h2 = (t2 / 12) & 3;
    int vp2 = t2 / 48;
    float s = 0.f;
#pragma unroll
    for (int ci = 0; ci < CC; ++ci)
      s = fmaf(x_s[ci * 24 + vp2 * 12 + l], wa[h2][which][ci], s);
    int slab = h2 * NBL + b * LL + l;
    float* dp = which ? s_dst : s_src;
    dp[slab * VV + v0 + vp2] = s;
  }
}

// ---------------------------------------------------------------------------
// k_slab: one WG per (bl, h, v-quarter). 1024 threads stage the full 62.5 KB
// f16 slab h_g[slab][*][*] into LDS (coalesced uint4), then each wave
// processes its v's: per 8-edge iter, csr load (L2) + s_dst load (L1-hot
// 4 KB row) + ee VALU + ONE ds_read_b64 (4 ch) + 4 fma_mix. All gathers hit
// LDS — no L2 round-trips in the dependent chain. Writes per-h partial
// h' = num/rs as f16 to tmp[slab][v][c]; cross-h mean done by k_fin.
// LDS 64000 B -> 2 WGs/CU (32 waves/CU).
// ---------------------------------------------------------------------------
__global__ __launch_bounds__(1024) void k_slab(const ushort* __restrict__ hg,
                                               const float* __restrict__ s_src,
                                               const float* __restrict__ s_dst,
                                               const int* __restrict__ cnt,
                                               const uint2* __restrict__ csr,
                                               ushort* __restrict__ tmp) {
  __shared__ ushort slab[VV * CC];        // 64000 B
  const int bl = blockIdx.x;              // 0..47
  const int h = blockIdx.y;               // 0..3
  const int quar = blockIdx.z;            // 0..3
  const int slabIdx = h * NBL + bl;
  const size_t sbase = (size_t)slabIdx * (VV * CC);

  {
    const uint4* src4 = (const uint4*)(hg + sbase);
    uint4* dst4 = (uint4*)slab;
    for (int i = threadIdx.x; i < VV * CC / 8; i += 1024) dst4[i] = src4[i];
  }
  __syncthreads();

  const float* sdb = s_dst + slabIdx * VV;   // 4 KB row, L1-resident
  const float* ssb = s_src + slabIdx * VV;
  const int wave = threadIdx.x >> 6;
  const int lane = threadIdx.x & 63;
  const int jj = lane >> 3;                  // 8 edge slots
  const int s2 = lane & 7;                   // 8 channel-quads (4 ch each)

  const int vend = quar * 250 + 250;
  for (int v = quar * 250 + wave; v < vend; v += 16) {
    int deg = cnt[v];
    if (deg > RCAP) deg = RCAP;
    float ssv = ssb[v];
    const int rbase = v * RCAP;

    float num0 = 0.f, num1 = 0.f, num2 = 0.f, num3 = 0.f, rs = 0.f;

    for (int p = 0; p < deg; p += 8) {
      int e = p + jj;
      bool valid = e < deg;
      uint2 ent = csr[rbase + (valid ? e : 0)];
      uint d = ent.x;
      float lv = __uint_as_float(ent.y);
      float s = ssv + sdb[d];
      float lr = fmaxf(s, LALPHA * s);
      float ee = __expf(-lr) * lv;
      ee = valid ? ee : 0.f;
      uint2 g = *(const uint2*)(slab + d * CC + s2 * 4);   // 4 f16 channels
      __half2 p0 = __builtin_bit_cast(__half2, g.x);
      __half2 p1 = __builtin_bit_cast(__half2, g.y);
      num0 = fmaf(ee, __low2float(p0), num0);
      num1 = fmaf(ee, __high2float(p0), num1);
      num2 = fmaf(ee, __low2float(p1), num2);
      num3 = fmaf(ee, __high2float(p1), num3);
      rs += ee;
    }

    // reduce over the 8 jj groups: xor 8, 16, 32
#pragma unroll
    for (int mm = 8; mm <= 32; mm <<= 1) {
      num0 += __shfl_xor(num0, mm);
      num1 += __shfl_xor(num1, mm);
      num2 += __shfl_xor(num2, mm);
      num3 += __shfl_xor(num3, mm);
      rs += __shfl_xor(rs, mm);
    }

    if (jj == 0) {
      float inv = __frcp_rn(rs);
      __half2 lo = __floats2half2_rn(num0 * inv, num1 * inv);
      __half2 hi = __floats2half2_rn(num2 * inv, num3 * inv);
      uint2 pk = make_uint2(__builtin_bit_cast(uint, lo),
                            __builtin_bit_cast(uint, hi));
      *(uint2*)(tmp + sbase + (size_t)v * CC + s2 * 4) = pk;
    }
  }
}

// ---------------------------------------------------------------------------
// k_fin: out[b][c][v][l] = elu(0.25 * sum_h tmp[h*48+b*12+l][v][c]);
// LDS transpose (r3-proven pattern, adapted to [slab][v][c] f16 tmp).
// ---------------------------------------------------------------------------
__global__ __launch_bounds__(256) void k_fin(const uint* __restrict__ tmp_u,
                                             float* __restrict__ outp) {
  __shared__ float t[CC][97];
  const int b = blockIdx.y;
  const int v0 = blockIdx.x * 8;
  const int tid = threadIdx.x;
  const int c2 = tid & 15, vi = (tid >> 4) & 7, half = tid >> 7;
#pragma unroll
  for (int li = 0; li < 6; ++li) {
    int l = half * 6 + li;
    float a0 = 0.f, a1 = 0.f;
#pragma unroll
    for (int h = 0; h < HH; ++h) {
      int slabIdx = h * NBL + b * LL + l;
      uint g = tmp_u[((size_t)slabIdx * VV + v0 + vi) * (CC / 2) + c2];
      __half2 p = __builtin_bit_cast(__half2, g);
      a0 += __low2float(p);
      a1 += __high2float(p);
    }
    a0 *= 0.25f;
    a1 *= 0.25f;
    a0 = a0 > 0.f ? a0 : expm1f(a0);
    a1 = a1 > 0.f ? a1 : expm1f(a1);
    t[2 * c2][vi * LL + l] = a0;
    t[2 * c2 + 1][vi * LL + l] = a1;
  }
  __syncthreads();
  {
    int c = tid >> 3, k = tid & 7;
    const float* src = &t[c][k * LL];
    float* op = &outp[((size_t)(b * CC + c) * VV + v0 + k) * LL];
#pragma unroll
    for (int j = 0; j < 3; ++j) {
      float4 w = {src[4 * j], src[4 * j + 1], src[4 * j + 2], src[4 * j + 3]};
      *(float4*)(op + 4 * j) = w;
    }
  }
}

// ---------------------------------------------------------------------------
extern "C" void kernel_launch(void* const* d_in, const int* in_sizes, int n_in,
                              void* d_out, int out_size, void* d_ws, size_t ws_size,
                              hipStream_t stream) {
  const float* x = (const float*)d_in[0];
  const float* W = (const float*)d_in[1];
  const float* a = (const float*)d_in[2];
  const int* ei = (const int*)d_in[3];
  const float* ev = (const float*)d_in[4];
  float* out = (float*)d_out;
  float* ws = (float*)d_ws;

  size_t o = 0;
  ushort* h_g = (ushort*)(ws + o);  o += (size_t)SS * VV * CC / 2;   // f16, 12.3 MB
  ushort* tmp = (ushort*)(ws + o);  o += (size_t)SS * VV * CC / 2;   // f16, 12.3 MB
  float* s_src = ws + o;            o += SS * VV;
  float* s_dst = ws + o;            o += SS * VV;
  int* cnt = (int*)(ws + o);        o += 1024;
  uint2* csr = (uint2*)(ws + o);    o += (size_t)VV * RCAP * 2;      // {dst, lv}

  hipMemsetAsync(cnt, 0, 1024 * sizeof(int), stream);

  dim3 gA(520, BB);   // x<500: h-projection; x>=500: edge scatter
  k_h<<<gA, 256, 0, stream>>>(x, W, a, h_g, s_src, s_dst, cnt, ei, ev, csr);

  k_slab<<<dim3(NBL, HH, 4), 1024, 0, stream>>>(h_g, s_src, s_dst, cnt, csr, tmp);

  k_fin<<<dim3(VV / 8, BB), 256, 0, stream>>>((const uint*)tmp, out);
}

// Round 11
// 63.281 us; speedup vs baseline: 1.4515x; 1.4515x over previous
//
#include <hip/hip_runtime.h>
#include <hip/hip_bf16.h>
#include <hip/hip_fp16.h>
#include <math.h>

#define HH 4
#define BB 4
#define CC 32
#define VV 1000
#define LL 12
#define EE 20000
#define NBL (BB * LL)   /* 48 */
#define SS (HH * NBL)   /* 192 */
#define RCAP 128        /* padded CSR row capacity (max deg ~45 for this input) */
#define LALPHA 0.2f
#define NEG_CAP_F -9000000000000000.0f

typedef unsigned int uint;
typedef unsigned short ushort;

// ---------------------------------------------------------------------------
// k_h (fused with scatter): blocks x<500 compute h_g/s_src/s_dst; blocks
// x>=500 do the padded-CSR scatter (cnt pre-zeroed by hipMemsetAsync).
// h_g[slab][v][c] (f16), slab=h*NBL+b*LL+l. Block = 2v x 4h x 32c.
// x rows read via wave-uniform base -> scalar (SMEM) loads, off the LDS pipe.
// ---------------------------------------------------------------------------
__global__ __launch_bounds__(256) void k_h(const float* __restrict__ x,
                                           const float* __restrict__ W,
                                           const float* __restrict__ a,
                                           ushort* __restrict__ h_g,
                                           float* __restrict__ s_src,
                                           float* __restrict__ s_dst,
                                           int* __restrict__ cnt,
                                           const int* __restrict__ ei,
                                           const float* __restrict__ ev,
                                           uint2* __restrict__ csr) {
  if (blockIdx.x >= 500) {
    int e = ((blockIdx.x - 500) * 4 + blockIdx.y) * 256 + threadIdx.x;
    if (e < EE) {
      int r = ei[e];
      int d = ei[EE + e];
      int pos = atomicAdd(&cnt[r], 1);
      if (pos < RCAP) {
        float lv = fmaxf(__logf(ev[e]), NEG_CAP_F);
        csr[r * RCAP + pos] = make_uint2((uint)d, __float_as_uint(lv));
      }
    }
    return;
  }

  __shared__ float W_lds[HH * CC * CC];   // 16 KB
  __shared__ float a_lds[HH * 2 * CC];    // 1 KB
  __shared__ float x_s[CC * 2 * LL];      // 3 KB (s-part only)
  __shared__ float wa[HH][2][CC];         // 512 B
  const int tid = threadIdx.x;
  const int b = blockIdx.y;
  const int v0 = blockIdx.x * 2;

  {
    const float4* Wf = (const float4*)W;
    float4* Wl = (float4*)W_lds;
    for (int i = tid; i < HH * CC * CC / 4; i += 256) Wl[i] = Wf[i];
  }
  a_lds[tid] = a[tid];   // HH*2*CC == 256
#pragma unroll
  for (int k = 0; k < 3; ++k) {
    int i = k * 256 + tid;
    int ci = i / 24, r = i - ci * 24;
    x_s[i] = x[(b * CC + ci) * (VV * LL) + v0 * LL + r];
  }
  __syncthreads();

  {
    int h = tid >> 6, which = (tid >> 5) & 1, ci = tid & 31;
    float acc = 0.f;
#pragma unroll
    for (int k = 0; k < CC; ++k) {
      int c = (k + ci) & 31;
      acc = fmaf(W_lds[h * CC * CC + ci * CC + c],
                 a_lds[h * 2 * CC + which * CC + c], acc);
    }
    wa[h][which][ci] = acc;
  }
  __syncthreads();

  const int vp = tid >> 7;          // wave-uniform
  const int h = (tid >> 5) & 3;
  const int c = tid & 31;
  const int v = v0 + vp;

  int xoff = (b * CC) * (VV * LL) + v * LL;
  xoff = __builtin_amdgcn_readfirstlane(xoff);
  const float* xr = x + xoff;

  float acc[LL];
#pragma unroll
  for (int l = 0; l < LL; ++l) acc[l] = 0.f;

#pragma unroll 4
  for (int ci = 0; ci < CC; ++ci) {
    float w = W_lds[h * CC * CC + ci * CC + c];
#pragma unroll
    for (int l = 0; l < LL; ++l)
      acc[l] = fmaf(xr[ci * (VV * LL) + l], w, acc[l]);
  }

  const int slab0 = h * NBL + b * LL;
#pragma unroll
  for (int l = 0; l < LL; ++l) {
    __half hv = __float2half(acc[l]);
    h_g[((size_t)(slab0 + l) * VV + v) * CC + c] = *(ushort*)&hv;
  }

  if (tid < 192) {
    int which = tid & 1;
    int t2 = tid >> 1;            // 0..95
    int l = t2 % 12;
    int h2 = (t2 / 12) & 3;
    int vp2 = t2 / 48;
    float s = 0.f;
#pragma unroll
    for (int ci = 0; ci < CC; ++ci)
      s = fmaf(x_s[ci * 24 + vp2 * 12 + l], wa[h2][which][ci], s);
    int slab = h2 * NBL + b * LL + l;
    float* dp = which ? s_dst : s_src;
    dp[slab * VV + v0 + vp2] = s;
  }
}

// ---------------------------------------------------------------------------
// k_agg: one wave per (v, bl); ZERO LDS. Phase A (16-edge chunk): lanes =
// 16 edges x 4 h -> one exp per (edge,h); every lane holds d for its ia
// (all ha-groups load identical csr entries). Phase B: lane = ii(4 slots) x
// h(4) x cg(4); per 4-edge iter the handoff is two ds_bpermute:
//   d2 = __shfl(d, idx), eh = __shfl(eev, (h<<4)|idx)   (idx = t*4+ii <= 15)
// then ONE dwordx4 gather (8 f16 ch) + 8 fma_mix. Slots >= m hold eev=0,
// d=0 -> contribute zero. Tail: xor-16/32 (slots) then xor-4/8 (heads),
// fused mean-over-h + ELU, 16 lanes write 2 dwords.
// XCD swizzle: same-bl stretches of 250 blocks per XCD slot (L2-resident).
// ---------------------------------------------------------------------------
__global__ __launch_bounds__(256) void k_agg(const ushort* __restrict__ hg,
                                             const float* __restrict__ s_src,
                                             const float* __restrict__ s_dst,
                                             const int* __restrict__ cnt,
                                             const uint2* __restrict__ csr,
                                             float* __restrict__ outp) {
  const int i = blockIdx.x;
  const int xcd = i & 7;
  const int q = i >> 3;                // 0..1499
  const int bl = xcd * 6 + q / 250;    // 0..47
  const int vb = q % 250;
  const int warp = threadIdx.x >> 6;
  const int v = vb * 4 + warp;
  const int lane = threadIdx.x & 63;
  const int b = bl / LL, l = bl - b * LL;

  int deg = cnt[v];
  if (deg > RCAP) deg = RCAP;
  const int rbase = v * RCAP;

  // phase-A role: lane = ha*16 + ia
  const int ha = lane >> 4;
  const int ia = lane & 15;
  const int slabA = ha * NBL + bl;
  const float ssv = s_src[slabA * VV + v];
  const float* sdbA = s_dst + slabA * VV;

  // phase-B role: lane = ii*16 + h*4 + cg
  const int ii = lane >> 4;
  const int h = (lane >> 2) & 3;
  const int cg = lane & 3;
  const int ehsrc = h << 4;            // shfl source base for ee

  const uint hoff = (uint)((h * NBL + bl) * (VV * CC * 2)) + (uint)(cg * 16);
  const char* hgbytes = (const char*)hg;

  float num[8];
#pragma unroll
  for (int j = 0; j < 8; ++j) num[j] = 0.f;
  float rs = 0.f;

  for (int base = 0; base < deg; base += 16) {
    // ---- phase A: one (edge,h) per lane, results stay in registers ----
    int e = base + ia;
    float eev = 0.f;
    int d = 0;
    if (e < deg) {
      uint2 ent = csr[rbase + e];
      d = (int)ent.x;
      float lv = __uint_as_float(ent.y);
      float s = ssv + sdbA[d];
      float lr = fmaxf(s, LALPHA * s);
      eev = __expf(-lr) * lv;
    }

    // ---- phase B: 4 edges x (4h x 32c) per iter, shfl handoff ----
    int m = deg - base;
    if (m > 16) m = 16;
    int iters = (m + 3) >> 2;
    for (int t = 0; t < iters; ++t) {
      int idx = (t << 2) + ii;         // <= 15 always
      int d2 = __shfl(d, idx);
      float eh = __shfl(eev, ehsrc | idx);
      uint voff = ((uint)d2 << 6) + hoff;
      uint4 g = *(const uint4*)(hgbytes + voff);   // 8 f16 channels
      __half2 p0 = __builtin_bit_cast(__half2, g.x);
      __half2 p1 = __builtin_bit_cast(__half2, g.y);
      __half2 p2 = __builtin_bit_cast(__half2, g.z);
      __half2 p3 = __builtin_bit_cast(__half2, g.w);
      num[0] = fmaf(eh, __low2float(p0), num[0]);
      num[1] = fmaf(eh, __high2float(p0), num[1]);
      num[2] = fmaf(eh, __low2float(p1), num[2]);
      num[3] = fmaf(eh, __high2float(p1), num[3]);
      num[4] = fmaf(eh, __low2float(p2), num[4]);
      num[5] = fmaf(eh, __high2float(p2), num[5]);
      num[6] = fmaf(eh, __low2float(p3), num[6]);
      num[7] = fmaf(eh, __high2float(p3), num[7]);
      rs += eh;
    }
  }

  // reduce over edge-slots (ii): xor 16, 32
#pragma unroll
  for (int mm = 16; mm <= 32; mm <<= 1) {
#pragma unroll
    for (int j = 0; j < 8; ++j) num[j] += __shfl_xor(num[j], mm);
    rs += __shfl_xor(rs, mm);
  }
  float inv = __frcp_rn(rs);
  float val[8];
#pragma unroll
  for (int j = 0; j < 8; ++j) val[j] = num[j] * inv;
  // reduce over heads (h bits): xor 4, 8
#pragma unroll
  for (int mm = 4; mm <= 8; mm <<= 1) {
#pragma unroll
    for (int j = 0; j < 8; ++j) val[j] += __shfl_xor(val[j], mm);
  }

  if (ii == 0) {
    int j0 = 2 * h;               // lane (h,cg) writes channels cg*8+2h, +1
    float a0 = val[j0] * 0.25f;
    float a1 = val[j0 + 1] * 0.25f;
    a0 = a0 > 0.f ? a0 : expm1f(a0);
    a1 = a1 > 0.f ? a1 : expm1f(a1);
    size_t o0 = ((size_t)(b * CC + cg * 8 + j0) * VV + v) * LL + l;
    outp[o0] = a0;
    outp[o0 + (size_t)VV * LL] = a1;
  }
}

// ---------------------------------------------------------------------------
extern "C" void kernel_launch(void* const* d_in, const int* in_sizes, int n_in,
                              void* d_out, int out_size, void* d_ws, size_t ws_size,
                              hipStream_t stream) {
  const float* x = (const float*)d_in[0];
  const float* W = (const float*)d_in[1];
  const float* a = (const float*)d_in[2];
  const int* ei = (const int*)d_in[3];
  const float* ev = (const float*)d_in[4];
  float* out = (float*)d_out;
  float* ws = (float*)d_ws;

  size_t o = 0;
  ushort* h_g = (ushort*)(ws + o);  o += (size_t)SS * VV * CC / 2;   // f16, 12.3 MB
  float* s_src = ws + o;            o += SS * VV;
  float* s_dst = ws + o;            o += SS * VV;
  int* cnt = (int*)(ws + o);        o += 1024;
  uint2* csr = (uint2*)(ws + o);    o += (size_t)VV * RCAP * 2;      // {dst, lv}

  hipMemsetAsync(cnt, 0, 1024 * sizeof(int), stream);

  dim3 gA(520, BB);   // x<500: h-projection; x>=500: edge scatter
  k_h<<<gA, 256, 0, stream>>>(x, W, a, h_g, s_src, s_dst, cnt, ei, ev, csr);

  k_agg<<<12000, 256, 0, stream>>>(h_g, s_src, s_dst, cnt, csr, out);
}